// Round 12
// baseline (553.831 us; speedup 1.0000x reference)
//
#include <hip/hip_runtime.h>
#include <hip/hip_bf16.h>

#define D 64
#define N_NODES 50000
#define N_EDGES 800000
#define TILE 32            // nodes per block tile (last tile has 16 valid rows)
#define SCAN_BLKS 196      // ceil(N/256)

// ---------------- degree histogram (standalone: atomics-only kernel) ----------------
__global__ void hist_k(const int* __restrict__ dst, int* __restrict__ cnt, int E) {
    int i = blockIdx.x * blockDim.x + threadIdx.x;
    if (i < E) atomicAdd(&cnt[dst[i]], 1);
}

// ---- helper: acc += s * w (componentwise) ----
__device__ __forceinline__ void fma4(float4& a, float s, float4 w) {
    a.x = fmaf(s, w.x, a.x);
    a.y = fmaf(s, w.y, a.y);
    a.z = fmaf(s, w.z, a.z);
    a.w = fmaf(s, w.w, a.w);
}

// ---- dense 32x64 tile GEMM out = hbuf @ W; 2 rows/thread sharing W loads ----
template <int SCALED>
__device__ __forceinline__ void tile_gemm32(const float (*hbuf)[68], const float4* __restrict__ W4,
                                            const float* __restrict__ dis, float* __restrict__ outp,
                                            int base, int t, int N) {
    int lane = t & 63;
    int cg = lane & 15;
    int rr = (t >> 6) * 4 + (lane >> 4);  // 0..15 (always valid: base+rr <= 49999)
    int r1 = rr + 16;                     // may be invalid in last tile
    float4 a0 = make_float4(0.f, 0.f, 0.f, 0.f);
    float4 a1 = make_float4(0.f, 0.f, 0.f, 0.f);
#pragma unroll
    for (int kk = 0; kk < 16; ++kk) {
        float4 h0 = *(const float4*)&hbuf[rr][kk * 4];
        float4 h1 = *(const float4*)&hbuf[r1][kk * 4];
        float4 w0 = W4[(kk * 4 + 0) * 16 + cg];
        float4 w1 = W4[(kk * 4 + 1) * 16 + cg];
        float4 w2 = W4[(kk * 4 + 2) * 16 + cg];
        float4 w3 = W4[(kk * 4 + 3) * 16 + cg];
        fma4(a0, h0.x, w0); fma4(a0, h0.y, w1); fma4(a0, h0.z, w2); fma4(a0, h0.w, w3);
        fma4(a1, h1.x, w0); fma4(a1, h1.y, w1); fma4(a1, h1.z, w2); fma4(a1, h1.w, w3);
    }
    if (SCALED) {
        float d0 = dis[base + rr];
        a0.x *= d0; a0.y *= d0; a0.z *= d0; a0.w *= d0;
    }
    ((float4*)outp)[(size_t)(base + rr) * 16 + cg] = a0;
    if (base + r1 < N) {
        if (SCALED) {
            float d1 = dis[base + r1];
            a1.x *= d1; a1.y *= d1; a1.z *= d1; a1.w *= d1;
        }
        ((float4*)outp)[(size_t)(base + r1) * 16 + cg] = a1;
    }
}

// ---------------- fused: scan1 (blocks < scanBlocks) || gemm0 (streaming+streaming) ----------------
// scan1: per-block exclusive scan of cnt -> off, block sums, dis = rsqrt(cnt+1)
// gemm0: H = x @ W0 (unscaled; scale fused into fill pass)
__global__ void scan1_gemm0_k(const int* __restrict__ cnt, int* __restrict__ off,
                              int* __restrict__ bsum, float* __restrict__ dis,
                              const float4* __restrict__ X4, const float4* __restrict__ W4,
                              float* __restrict__ H, int N, int scanBlocks) {
    __shared__ float hbuf[TILE][68];
    int bid = blockIdx.x;
    int t = threadIdx.x;
    if (bid < scanBlocks) {
        int* sh = (int*)hbuf;
        int i = bid * 256 + t;
        int v = (i < N) ? cnt[i] : 0;
        sh[t] = v;
        __syncthreads();
#pragma unroll
        for (int d = 1; d < 256; d <<= 1) {
            int u = (t >= d) ? sh[t - d] : 0;
            __syncthreads();
            sh[t] += u;
            __syncthreads();
        }
        if (i < N) {
            off[i] = sh[t] - v;
            dis[i] = rsqrtf((float)v + 1.0f);  // +1 self loop
        }
        if (t == 255) bsum[bid] = sh[255];
    } else {
        int base = (bid - scanBlocks) * TILE;
        for (int idx = t; idx < TILE * 16; idx += 256) {
            int r = idx >> 4, ch = idx & 15;
            float4 v = (base + r < N) ? X4[(size_t)(base + r) * 16 + ch]
                                      : make_float4(0.f, 0.f, 0.f, 0.f);
            *(float4*)&hbuf[r][ch * 4] = v;
        }
        __syncthreads();
        tile_gemm32<0>(hbuf, W4, nullptr, H, base, t, N);
    }
}

// ---------------- scan3 (scan2 replicated per block): finalize off, init cursor ----------------
__global__ void scan3_k(int* __restrict__ off, const int* __restrict__ bsum,
                        int* __restrict__ cursor, int N, int E, int nb) {
    __shared__ int sh[256];
    int t = threadIdx.x;
    int v = (t < nb) ? bsum[t] : 0;
    sh[t] = v;
    __syncthreads();
#pragma unroll
    for (int d = 1; d < 256; d <<= 1) {
        int u = (t >= d) ? sh[t - d] : 0;
        __syncthreads();
        sh[t] += u;
        __syncthreads();
    }
    int add = (blockIdx.x == 0) ? 0 : sh[blockIdx.x - 1];
    int i = blockIdx.x * 256 + t;
    if (i < N) {
        int o = off[i] + add;
        off[i] = o;
        cursor[i] = o;
    }
    if (i == 0) off[N] = E;
}

// ---------------- fused: CSR fill (1 edge/thread) || H *= dis[row] ----------------
__global__ void fused_fill_k(const int* __restrict__ src, const int* __restrict__ dst,
                             int* __restrict__ cursor, int* __restrict__ esrc,
                             float4* __restrict__ H4, const float* __restrict__ dis,
                             int N, int E, int fillBlocks) {
    int bid = blockIdx.x;
    int t = threadIdx.x;
    if (bid < fillBlocks) {
        for (int i = bid * 256 + t; i < E; i += fillBlocks * 256) {
            int pos = atomicAdd(&cursor[dst[i]], 1);
            esrc[pos] = src[i];
        }
    } else {
        int sb = bid - fillBlocks;
        int nsb = gridDim.x - fillBlocks;
        int total = N * 16;  // float4 elements
        for (int i = sb * 256 + t; i < total; i += nsb * 256) {
            float4 v = H4[i];
            float dv = dis[i >> 4];
            v.x *= dv; v.y *= dv; v.z *= dv; v.w *= dv;
            H4[i] = v;
        }
    }
}

// ---- gather helpers: unconditional batch of 8, predicated tail batch ----
__device__ __forceinline__ void batch8(const float4* __restrict__ Hs4,
                                       const int* __restrict__ esrc,
                                       int j, int l16, float4& acc) {
    int s0 = esrc[j],     s1 = esrc[j + 1], s2 = esrc[j + 2], s3 = esrc[j + 3];
    int s4 = esrc[j + 4], s5 = esrc[j + 5], s6 = esrc[j + 6], s7 = esrc[j + 7];
    float4 v0 = Hs4[(size_t)s0 * 16 + l16];
    float4 v1 = Hs4[(size_t)s1 * 16 + l16];
    float4 v2 = Hs4[(size_t)s2 * 16 + l16];
    float4 v3 = Hs4[(size_t)s3 * 16 + l16];
    float4 v4 = Hs4[(size_t)s4 * 16 + l16];
    float4 v5 = Hs4[(size_t)s5 * 16 + l16];
    float4 v6 = Hs4[(size_t)s6 * 16 + l16];
    float4 v7 = Hs4[(size_t)s7 * 16 + l16];
    acc.x += ((v0.x + v1.x) + (v2.x + v3.x)) + ((v4.x + v5.x) + (v6.x + v7.x));
    acc.y += ((v0.y + v1.y) + (v2.y + v3.y)) + ((v4.y + v5.y) + (v6.y + v7.y));
    acc.z += ((v0.z + v1.z) + (v2.z + v3.z)) + ((v4.z + v5.z) + (v6.z + v7.z));
    acc.w += ((v0.w + v1.w) + (v2.w + v3.w)) + ((v4.w + v5.w) + (v6.w + v7.w));
}

__device__ __forceinline__ void tail8(const float4* __restrict__ Hs4,
                                      const int* __restrict__ esrc,
                                      int j, int end, int l16, float4& acc) {
    if (j >= end) return;
    int last = end - 1;
    int i1 = j + 1 <= last ? j + 1 : last;
    int i2 = j + 2 <= last ? j + 2 : last;
    int i3 = j + 3 <= last ? j + 3 : last;
    int i4 = j + 4 <= last ? j + 4 : last;
    int i5 = j + 5 <= last ? j + 5 : last;
    int i6 = j + 6 <= last ? j + 6 : last;
    int i7 = j + 7 <= last ? j + 7 : last;
    int s0 = esrc[j],  s1 = esrc[i1], s2 = esrc[i2], s3 = esrc[i3];
    int s4 = esrc[i4], s5 = esrc[i5], s6 = esrc[i6], s7 = esrc[i7];
    float m1 = (j + 1 < end) ? 1.f : 0.f;
    float m2 = (j + 2 < end) ? 1.f : 0.f;
    float m3 = (j + 3 < end) ? 1.f : 0.f;
    float m4 = (j + 4 < end) ? 1.f : 0.f;
    float m5 = (j + 5 < end) ? 1.f : 0.f;
    float m6 = (j + 6 < end) ? 1.f : 0.f;
    float m7 = (j + 7 < end) ? 1.f : 0.f;
    float4 v0 = Hs4[(size_t)s0 * 16 + l16];
    float4 v1 = Hs4[(size_t)s1 * 16 + l16];
    float4 v2 = Hs4[(size_t)s2 * 16 + l16];
    float4 v3 = Hs4[(size_t)s3 * 16 + l16];
    float4 v4 = Hs4[(size_t)s4 * 16 + l16];
    float4 v5 = Hs4[(size_t)s5 * 16 + l16];
    float4 v6 = Hs4[(size_t)s6 * 16 + l16];
    float4 v7 = Hs4[(size_t)s7 * 16 + l16];
    acc.x += v0.x; acc.y += v0.y; acc.z += v0.z; acc.w += v0.w;
    acc.x = fmaf(m1, v1.x, acc.x); acc.y = fmaf(m1, v1.y, acc.y); acc.z = fmaf(m1, v1.z, acc.z); acc.w = fmaf(m1, v1.w, acc.w);
    acc.x = fmaf(m2, v2.x, acc.x); acc.y = fmaf(m2, v2.y, acc.y); acc.z = fmaf(m2, v2.z, acc.z); acc.w = fmaf(m2, v2.w, acc.w);
    acc.x = fmaf(m3, v3.x, acc.x); acc.y = fmaf(m3, v3.y, acc.y); acc.z = fmaf(m3, v3.z, acc.z); acc.w = fmaf(m3, v3.w, acc.w);
    acc.x = fmaf(m4, v4.x, acc.x); acc.y = fmaf(m4, v4.y, acc.y); acc.z = fmaf(m4, v4.z, acc.z); acc.w = fmaf(m4, v4.w, acc.w);
    acc.x = fmaf(m5, v5.x, acc.x); acc.y = fmaf(m5, v5.y, acc.y); acc.z = fmaf(m5, v5.z, acc.z); acc.w = fmaf(m5, v5.w, acc.w);
    acc.x = fmaf(m6, v6.x, acc.x); acc.y = fmaf(m6, v6.y, acc.y); acc.z = fmaf(m6, v6.z, acc.z); acc.w = fmaf(m6, v6.w, acc.w);
    acc.x = fmaf(m7, v7.x, acc.x); acc.y = fmaf(m7, v7.y, acc.y); acc.z = fmaf(m7, v7.z, acc.z); acc.w = fmaf(m7, v7.w, acc.w);
}

// ---------------- fused layer: 2-node interleaved gather + activation + tile GEMM / projection ----------------
// 32 nodes per block; each 16-lane group owns nodes nA=base+rloc and nB=nA+16,
// interleaving their edge batches for 2x memory-level parallelism.
template <int FINAL>
__global__ void layer_k(const float4* __restrict__ Hs4, const int* __restrict__ off,
                        const int* __restrict__ esrc, const float* __restrict__ dis,
                        const float* __restrict__ bias, const float4* __restrict__ W4,
                        const float* __restrict__ bout, float* __restrict__ outp, int N) {
    int t = threadIdx.x;
    int lane = t & 63;
    int w = t >> 6;
    int g = lane >> 4;
    int l16 = lane & 15;
    int rloc = w * 4 + g;               // 0..15
    int base = blockIdx.x * TILE;
    int nA = base + rloc;               // always < N (base <= 49984, rloc <= 15)
    int nB = nA + 16;
    bool vB = (nB < N);

    int begA = off[nA], endA = off[nA + 1];
    float4 accA = Hs4[(size_t)nA * 16 + l16];  // self-loop term
    int begB = 0, endB = 0;
    float4 accB = make_float4(0.f, 0.f, 0.f, 0.f);
    if (vB) {
        begB = off[nB]; endB = off[nB + 1];
        accB = Hs4[(size_t)nB * 16 + l16];
    }

    int jA = begA, jB = begB;
    while (jA + 8 <= endA && jB + 8 <= endB) {  // interleaved: 16 loads in flight
        batch8(Hs4, esrc, jA, l16, accA);
        batch8(Hs4, esrc, jB, l16, accB);
        jA += 8; jB += 8;
    }
    while (jA + 8 <= endA) { batch8(Hs4, esrc, jA, l16, accA); jA += 8; }
    while (jB + 8 <= endB) { batch8(Hs4, esrc, jB, l16, accB); jB += 8; }
    tail8(Hs4, esrc, jA, endA, l16, accA);
    tail8(Hs4, esrc, jB, endB, l16, accB);

    // ---- activation: h = relu(agg * dis + b) ----
    float dvA = dis[nA];
    float dvB = vB ? dis[nB] : 0.f;
    float4 b4 = ((const float4*)bias)[l16];
    float4 hA, hB;
    hA.x = fmaxf(fmaf(accA.x, dvA, b4.x), 0.f);
    hA.y = fmaxf(fmaf(accA.y, dvA, b4.y), 0.f);
    hA.z = fmaxf(fmaf(accA.z, dvA, b4.z), 0.f);
    hA.w = fmaxf(fmaf(accA.w, dvA, b4.w), 0.f);
    hB.x = fmaxf(fmaf(accB.x, dvB, b4.x), 0.f);
    hB.y = fmaxf(fmaf(accB.y, dvB, b4.y), 0.f);
    hB.z = fmaxf(fmaf(accB.z, dvB, b4.z), 0.f);
    hB.w = fmaxf(fmaf(accB.w, dvB, b4.w), 0.f);

    if (FINAL) {
        float4 w4 = ((const float4*)W4)[l16];
        float pA = fmaf(hA.x, w4.x, fmaf(hA.y, w4.y, fmaf(hA.z, w4.z, hA.w * w4.w)));
        float pB = fmaf(hB.x, w4.x, fmaf(hB.y, w4.y, fmaf(hB.z, w4.z, hB.w * w4.w)));
        pA += __shfl_xor(pA, 1, 64);  pB += __shfl_xor(pB, 1, 64);
        pA += __shfl_xor(pA, 2, 64);  pB += __shfl_xor(pB, 2, 64);
        pA += __shfl_xor(pA, 4, 64);  pB += __shfl_xor(pB, 4, 64);
        pA += __shfl_xor(pA, 8, 64);  pB += __shfl_xor(pB, 8, 64);
        if (l16 == 0) {
            float b = bout[0];
            outp[nA] = pA + b;
            if (vB) outp[nB] = pB + b;
        }
    } else {
        __shared__ float hbuf[TILE][68];
        *(float4*)&hbuf[rloc][l16 * 4] = hA;
        *(float4*)&hbuf[rloc + 16][l16 * 4] = hB;
        __syncthreads();
        tile_gemm32<1>(hbuf, W4, dis, outp, base, t, N);
    }
}

extern "C" void kernel_launch(void* const* d_in, const int* in_sizes, int n_in,
                              void* d_out, int out_size, void* d_ws, size_t ws_size,
                              hipStream_t stream) {
    const float* x    = (const float*)d_in[0];
    const int*   ei   = (const int*)d_in[1];
    const float* W0   = (const float*)d_in[2];
    const float* b0   = (const float*)d_in[3];
    const float* W1   = (const float*)d_in[4];
    const float* b1   = (const float*)d_in[5];
    const float* W2   = (const float*)d_in[6];
    const float* b2   = (const float*)d_in[7];
    const float* Wout = (const float*)d_in[8];
    const float* bout = (const float*)d_in[9];
    float* out = (float*)d_out;

    const int N = N_NODES, E = N_EDGES;
    const int* src = ei;
    const int* dst = ei + E;

    // ws layout (byte offsets) — verified no overlaps:
    //   cnt    [0,        200000)
    //   off    [262144,   462148)   (N+1 ints)
    //   cursor [524288,   724288)
    //   dis    [786432,   986432)
    //   bsum   [1013760,  1014784)  (990 KiB)
    //   esrc   [1048576,  4248576)  (E ints)
    //   bufA   [5 MiB,    +12.8 MB)
    //   bufB   [18 MiB,   +12.8 MB)
    char* ws = (char*)d_ws;
    int*   cnt    = (int*)(ws);
    int*   off    = (int*)(ws + (256u << 10));
    int*   cursor = (int*)(ws + (512u << 10));
    float* dis    = (float*)(ws + (768u << 10));
    int*   bsum   = (int*)(ws + (990u << 10));
    int*   esrc   = (int*)(ws + (1u << 20));
    float* bufA   = (float*)(ws + (5u << 20));
    float* bufB   = (float*)(ws + (18u << 20));

    dim3 blk(256);
    dim3 gE((E + 255) / 256);            // 3125 (1 edge/thread)
    const int TILES = (N + TILE - 1) / TILE;  // 1563 (last tile: 16 valid rows)
    dim3 gTile(TILES);
    const int FILL_BLOCKS = 3125;
    const int SCALE_BLOCKS = 784;

    // ---- prelude ----
    hipMemsetAsync(cnt, 0, (size_t)N * sizeof(int), stream);
    hist_k<<<gE, blk, 0, stream>>>(dst, cnt, E);

    // scan1 (196 blocks) || gemm0 (1563 blocks) — both streaming roles
    scan1_gemm0_k<<<dim3(SCAN_BLKS + TILES), blk, 0, stream>>>(
        cnt, off, bsum, dis, (const float4*)x, (const float4*)W0, bufA, N, SCAN_BLKS);

    // scan3 (scan2 replicated inside each block)
    scan3_k<<<dim3(SCAN_BLKS), blk, 0, stream>>>(off, bsum, cursor, N, E, SCAN_BLKS);

    // ---- CSR fill || H *= dis[row] ----
    fused_fill_k<<<dim3(FILL_BLOCKS + SCALE_BLOCKS), blk, 0, stream>>>(
        src, dst, cursor, esrc, (float4*)bufA, dis, N, E, FILL_BLOCKS);

    // ---- fused layers: gather + relu(bias,dis) + next GEMM ----
    layer_k<0><<<gTile, blk, 0, stream>>>((const float4*)bufA, off, esrc, dis,
                                          b0, (const float4*)W1, nullptr, bufB, N);
    layer_k<0><<<gTile, blk, 0, stream>>>((const float4*)bufB, off, esrc, dis,
                                          b1, (const float4*)W2, nullptr, bufA, N);
    // ---- final: gather + relu + projection ----
    layer_k<1><<<gTile, blk, 0, stream>>>((const float4*)bufA, off, esrc, dis,
                                          b2, (const float4*)Wout, bout, out, N);
}

// Round 13
// 376.308 us; speedup vs baseline: 1.4717x; 1.4717x over previous
//
#include <hip/hip_runtime.h>
#include <hip/hip_bf16.h>

#define D 64
#define N_NODES 50000
#define N_EDGES 800000
#define TILE 16            // nodes per layer-block (N % 16 == 0 -> no tails)
#define GTILE 32           // nodes per gemm0 tile (last tile has 16 valid rows)
#define SCAN_BLKS 196      // ceil(N/256)

// ---------------- degree histogram (standalone: atomics-only kernel) ----------------
__global__ void hist_k(const int* __restrict__ dst, int* __restrict__ cnt, int E) {
    int i = blockIdx.x * blockDim.x + threadIdx.x;
    if (i < E) atomicAdd(&cnt[dst[i]], 1);
}

// ---- helper: acc += s * w (componentwise) ----
__device__ __forceinline__ void fma4(float4& a, float s, float4 w) {
    a.x = fmaf(s, w.x, a.x);
    a.y = fmaf(s, w.y, a.y);
    a.z = fmaf(s, w.z, a.z);
    a.w = fmaf(s, w.w, a.w);
}

// ---- dense 16x64 tile GEMM out = hbuf @ W, optionally scaled by dis[row] ----
template <int SCALED>
__device__ __forceinline__ void tile_gemm(const float (*hbuf)[68], const float4* __restrict__ W4,
                                          const float* __restrict__ dis, float* __restrict__ outp,
                                          int base, int t) {
    int lane = t & 63;
    int cg = lane & 15;
    int rr = (t >> 6) * 4 + (lane >> 4);
    float4 acc = make_float4(0.f, 0.f, 0.f, 0.f);
#pragma unroll
    for (int kk = 0; kk < 16; ++kk) {
        float4 hb = *(const float4*)&hbuf[rr][kk * 4];
        fma4(acc, hb.x, W4[(kk * 4 + 0) * 16 + cg]);
        fma4(acc, hb.y, W4[(kk * 4 + 1) * 16 + cg]);
        fma4(acc, hb.z, W4[(kk * 4 + 2) * 16 + cg]);
        fma4(acc, hb.w, W4[(kk * 4 + 3) * 16 + cg]);
    }
    if (SCALED) {
        float dv = dis[base + rr];
        acc.x *= dv; acc.y *= dv; acc.z *= dv; acc.w *= dv;
    }
    ((float4*)outp)[(size_t)(base + rr) * 16 + cg] = acc;
}

// ---- dense 32x64 tile GEMM (gemm0 role): 2 rows/thread sharing W loads ----
__device__ __forceinline__ void tile_gemm32(const float (*hbuf)[68], const float4* __restrict__ W4,
                                            float* __restrict__ outp, int base, int t, int N) {
    int lane = t & 63;
    int cg = lane & 15;
    int rr = (t >> 6) * 4 + (lane >> 4);  // 0..15
    int r1 = rr + 16;
    float4 a0 = make_float4(0.f, 0.f, 0.f, 0.f);
    float4 a1 = make_float4(0.f, 0.f, 0.f, 0.f);
#pragma unroll
    for (int kk = 0; kk < 16; ++kk) {
        float4 h0 = *(const float4*)&hbuf[rr][kk * 4];
        float4 h1 = *(const float4*)&hbuf[r1][kk * 4];
        float4 w0 = W4[(kk * 4 + 0) * 16 + cg];
        float4 w1 = W4[(kk * 4 + 1) * 16 + cg];
        float4 w2 = W4[(kk * 4 + 2) * 16 + cg];
        float4 w3 = W4[(kk * 4 + 3) * 16 + cg];
        fma4(a0, h0.x, w0); fma4(a0, h0.y, w1); fma4(a0, h0.z, w2); fma4(a0, h0.w, w3);
        fma4(a1, h1.x, w0); fma4(a1, h1.y, w1); fma4(a1, h1.z, w2); fma4(a1, h1.w, w3);
    }
    ((float4*)outp)[(size_t)(base + rr) * 16 + cg] = a0;
    if (base + r1 < N)
        ((float4*)outp)[(size_t)(base + r1) * 16 + cg] = a1;
}

// ---------------- fused: scan1 (blocks < scanBlocks) || gemm0 (streaming+streaming) ----------------
__global__ void scan1_gemm0_k(const int* __restrict__ cnt, int* __restrict__ off,
                              int* __restrict__ bsum, float* __restrict__ dis,
                              const float4* __restrict__ X4, const float4* __restrict__ W4,
                              float* __restrict__ H, int N, int scanBlocks) {
    __shared__ float hbuf[GTILE][68];
    int bid = blockIdx.x;
    int t = threadIdx.x;
    if (bid < scanBlocks) {
        int* sh = (int*)hbuf;
        int i = bid * 256 + t;
        int v = (i < N) ? cnt[i] : 0;
        sh[t] = v;
        __syncthreads();
#pragma unroll
        for (int d = 1; d < 256; d <<= 1) {
            int u = (t >= d) ? sh[t - d] : 0;
            __syncthreads();
            sh[t] += u;
            __syncthreads();
        }
        if (i < N) {
            off[i] = sh[t] - v;
            dis[i] = rsqrtf((float)v + 1.0f);  // +1 self loop
        }
        if (t == 255) bsum[bid] = sh[255];
    } else {
        int base = (bid - scanBlocks) * GTILE;
        for (int idx = t; idx < GTILE * 16; idx += 256) {
            int r = idx >> 4, ch = idx & 15;
            float4 v = (base + r < N) ? X4[(size_t)(base + r) * 16 + ch]
                                      : make_float4(0.f, 0.f, 0.f, 0.f);
            *(float4*)&hbuf[r][ch * 4] = v;
        }
        __syncthreads();
        tile_gemm32(hbuf, W4, H, base, t, N);
    }
}

// ---------------- scan3 (scan2 replicated per block): finalize off, init cursor ----------------
__global__ void scan3_k(int* __restrict__ off, const int* __restrict__ bsum,
                        int* __restrict__ cursor, int N, int E, int nb) {
    __shared__ int sh[256];
    int t = threadIdx.x;
    int v = (t < nb) ? bsum[t] : 0;
    sh[t] = v;
    __syncthreads();
#pragma unroll
    for (int d = 1; d < 256; d <<= 1) {
        int u = (t >= d) ? sh[t - d] : 0;
        __syncthreads();
        sh[t] += u;
        __syncthreads();
    }
    int add = (blockIdx.x == 0) ? 0 : sh[blockIdx.x - 1];
    int i = blockIdx.x * 256 + t;
    if (i < N) {
        int o = off[i] + add;
        off[i] = o;
        cursor[i] = o;
    }
    if (i == 0) off[N] = E;
}

// ---------------- fused: CSR fill (1 edge/thread) || H *= dis[row] ----------------
__global__ void fused_fill_k(const int* __restrict__ src, const int* __restrict__ dst,
                             int* __restrict__ cursor, int* __restrict__ esrc,
                             float4* __restrict__ H4, const float* __restrict__ dis,
                             int N, int E, int fillBlocks) {
    int bid = blockIdx.x;
    int t = threadIdx.x;
    if (bid < fillBlocks) {
        for (int i = bid * 256 + t; i < E; i += fillBlocks * 256) {
            int pos = atomicAdd(&cursor[dst[i]], 1);
            esrc[pos] = src[i];
        }
    } else {
        int sb = bid - fillBlocks;
        int nsb = gridDim.x - fillBlocks;
        int total = N * 16;  // float4 elements
        for (int i = sb * 256 + t; i < total; i += nsb * 256) {
            float4 v = H4[i];
            float dv = dis[i >> 4];
            v.x *= dv; v.y *= dv; v.z *= dv; v.w *= dv;
            H4[i] = v;
        }
    }
}

// ---------------- fused layer (round-11 proven): group-gather + activation + tile GEMM / projection ----------------
// 16 nodes per block; each 16-lane group gathers one node (lane owns a float4 chunk).
// Gather: unconditional batches of 8, then ONE predicated tail batch (no serial remainder).
template <int FINAL>
__global__ void layer_k(const float4* __restrict__ Hs4, const int* __restrict__ off,
                        const int* __restrict__ esrc, const float* __restrict__ dis,
                        const float* __restrict__ bias, const float4* __restrict__ W4,
                        const float* __restrict__ bout, float* __restrict__ outp, int N) {
    __shared__ float hbuf[TILE][68];
    int t = threadIdx.x;
    int lane = t & 63;
    int w = t >> 6;
    int g = lane >> 4;
    int l16 = lane & 15;
    int rloc = w * 4 + g;
    int n = blockIdx.x * TILE + rloc;

    int beg = off[n], end = off[n + 1];
    float4 acc = Hs4[(size_t)n * 16 + l16];  // self-loop term
    int j = beg;
    for (; j + 8 <= end; j += 8) {
        int s0 = esrc[j],     s1 = esrc[j + 1], s2 = esrc[j + 2], s3 = esrc[j + 3];
        int s4 = esrc[j + 4], s5 = esrc[j + 5], s6 = esrc[j + 6], s7 = esrc[j + 7];
        float4 v0 = Hs4[(size_t)s0 * 16 + l16];
        float4 v1 = Hs4[(size_t)s1 * 16 + l16];
        float4 v2 = Hs4[(size_t)s2 * 16 + l16];
        float4 v3 = Hs4[(size_t)s3 * 16 + l16];
        float4 v4 = Hs4[(size_t)s4 * 16 + l16];
        float4 v5 = Hs4[(size_t)s5 * 16 + l16];
        float4 v6 = Hs4[(size_t)s6 * 16 + l16];
        float4 v7 = Hs4[(size_t)s7 * 16 + l16];
        acc.x += ((v0.x + v1.x) + (v2.x + v3.x)) + ((v4.x + v5.x) + (v6.x + v7.x));
        acc.y += ((v0.y + v1.y) + (v2.y + v3.y)) + ((v4.y + v5.y) + (v6.y + v7.y));
        acc.z += ((v0.z + v1.z) + (v2.z + v3.z)) + ((v4.z + v5.z) + (v6.z + v7.z));
        acc.w += ((v0.w + v1.w) + (v2.w + v3.w)) + ((v4.w + v5.w) + (v6.w + v7.w));
    }
    if (j < end) {
        int last = end - 1;
        int i1 = j + 1 <= last ? j + 1 : last;
        int i2 = j + 2 <= last ? j + 2 : last;
        int i3 = j + 3 <= last ? j + 3 : last;
        int i4 = j + 4 <= last ? j + 4 : last;
        int i5 = j + 5 <= last ? j + 5 : last;
        int i6 = j + 6 <= last ? j + 6 : last;
        int i7 = j + 7 <= last ? j + 7 : last;
        int s0 = esrc[j],  s1 = esrc[i1], s2 = esrc[i2], s3 = esrc[i3];
        int s4 = esrc[i4], s5 = esrc[i5], s6 = esrc[i6], s7 = esrc[i7];
        float m1 = (j + 1 < end) ? 1.f : 0.f;
        float m2 = (j + 2 < end) ? 1.f : 0.f;
        float m3 = (j + 3 < end) ? 1.f : 0.f;
        float m4 = (j + 4 < end) ? 1.f : 0.f;
        float m5 = (j + 5 < end) ? 1.f : 0.f;
        float m6 = (j + 6 < end) ? 1.f : 0.f;
        float m7 = (j + 7 < end) ? 1.f : 0.f;
        float4 v0 = Hs4[(size_t)s0 * 16 + l16];
        float4 v1 = Hs4[(size_t)s1 * 16 + l16];
        float4 v2 = Hs4[(size_t)s2 * 16 + l16];
        float4 v3 = Hs4[(size_t)s3 * 16 + l16];
        float4 v4 = Hs4[(size_t)s4 * 16 + l16];
        float4 v5 = Hs4[(size_t)s5 * 16 + l16];
        float4 v6 = Hs4[(size_t)s6 * 16 + l16];
        float4 v7 = Hs4[(size_t)s7 * 16 + l16];
        acc.x += v0.x; acc.y += v0.y; acc.z += v0.z; acc.w += v0.w;
        acc.x = fmaf(m1, v1.x, acc.x); acc.y = fmaf(m1, v1.y, acc.y); acc.z = fmaf(m1, v1.z, acc.z); acc.w = fmaf(m1, v1.w, acc.w);
        acc.x = fmaf(m2, v2.x, acc.x); acc.y = fmaf(m2, v2.y, acc.y); acc.z = fmaf(m2, v2.z, acc.z); acc.w = fmaf(m2, v2.w, acc.w);
        acc.x = fmaf(m3, v3.x, acc.x); acc.y = fmaf(m3, v3.y, acc.y); acc.z = fmaf(m3, v3.z, acc.z); acc.w = fmaf(m3, v3.w, acc.w);
        acc.x = fmaf(m4, v4.x, acc.x); acc.y = fmaf(m4, v4.y, acc.y); acc.z = fmaf(m4, v4.z, acc.z); acc.w = fmaf(m4, v4.w, acc.w);
        acc.x = fmaf(m5, v5.x, acc.x); acc.y = fmaf(m5, v5.y, acc.y); acc.z = fmaf(m5, v5.z, acc.z); acc.w = fmaf(m5, v5.w, acc.w);
        acc.x = fmaf(m6, v6.x, acc.x); acc.y = fmaf(m6, v6.y, acc.y); acc.z = fmaf(m6, v6.z, acc.z); acc.w = fmaf(m6, v6.w, acc.w);
        acc.x = fmaf(m7, v7.x, acc.x); acc.y = fmaf(m7, v7.y, acc.y); acc.z = fmaf(m7, v7.z, acc.z); acc.w = fmaf(m7, v7.w, acc.w);
    }

    // ---- activation: h = relu(agg * dis[n] + b) ----
    float dv = dis[n];
    float4 b4 = ((const float4*)bias)[l16];
    float4 h4;
    h4.x = fmaxf(fmaf(acc.x, dv, b4.x), 0.f);
    h4.y = fmaxf(fmaf(acc.y, dv, b4.y), 0.f);
    h4.z = fmaxf(fmaf(acc.z, dv, b4.z), 0.f);
    h4.w = fmaxf(fmaf(acc.w, dv, b4.w), 0.f);

    if (FINAL) {
        float4 w4 = ((const float4*)W4)[l16];
        float p = fmaf(h4.x, w4.x, fmaf(h4.y, w4.y, fmaf(h4.z, w4.z, h4.w * w4.w)));
        p += __shfl_xor(p, 1, 64);
        p += __shfl_xor(p, 2, 64);
        p += __shfl_xor(p, 4, 64);
        p += __shfl_xor(p, 8, 64);
        if (l16 == 0) outp[n] = p + bout[0];
    } else {
        *(float4*)&hbuf[rloc][l16 * 4] = h4;
        __syncthreads();
        tile_gemm<1>(hbuf, W4, dis, outp, blockIdx.x * TILE, t);
    }
}

extern "C" void kernel_launch(void* const* d_in, const int* in_sizes, int n_in,
                              void* d_out, int out_size, void* d_ws, size_t ws_size,
                              hipStream_t stream) {
    const float* x    = (const float*)d_in[0];
    const int*   ei   = (const int*)d_in[1];
    const float* W0   = (const float*)d_in[2];
    const float* b0   = (const float*)d_in[3];
    const float* W1   = (const float*)d_in[4];
    const float* b1   = (const float*)d_in[5];
    const float* W2   = (const float*)d_in[6];
    const float* b2   = (const float*)d_in[7];
    const float* Wout = (const float*)d_in[8];
    const float* bout = (const float*)d_in[9];
    float* out = (float*)d_out;

    const int N = N_NODES, E = N_EDGES;
    const int* src = ei;
    const int* dst = ei + E;

    // ws layout (byte offsets) — verified no overlaps:
    //   cnt    [0,        200000)
    //   off    [262144,   462148)   (N+1 ints)
    //   cursor [524288,   724288)
    //   dis    [786432,   986432)
    //   bsum   [1013760,  1014784)  (990 KiB)
    //   esrc   [1048576,  4248576)  (E ints)
    //   bufA   [5 MiB,    +12.8 MB)
    //   bufB   [18 MiB,   +12.8 MB)
    char* ws = (char*)d_ws;
    int*   cnt    = (int*)(ws);
    int*   off    = (int*)(ws + (256u << 10));
    int*   cursor = (int*)(ws + (512u << 10));
    float* dis    = (float*)(ws + (768u << 10));
    int*   bsum   = (int*)(ws + (990u << 10));
    int*   esrc   = (int*)(ws + (1u << 20));
    float* bufA   = (float*)(ws + (5u << 20));
    float* bufB   = (float*)(ws + (18u << 20));

    dim3 blk(256);
    dim3 gE((E + 255) / 256);                  // 3125 (1 edge/thread)
    const int LTILES = N / TILE;               // 3125 (exact, layer grid)
    dim3 gLayer(LTILES);
    const int GTILES = (N + GTILE - 1) / GTILE; // 1563 (gemm0 role)
    const int FILL_BLOCKS = 3125;
    const int SCALE_BLOCKS = 784;

    // ---- prelude ----
    hipMemsetAsync(cnt, 0, (size_t)N * sizeof(int), stream);
    hist_k<<<gE, blk, 0, stream>>>(dst, cnt, E);

    // scan1 (196 blocks) || gemm0 (1563 blocks) — both streaming roles
    scan1_gemm0_k<<<dim3(SCAN_BLKS + GTILES), blk, 0, stream>>>(
        cnt, off, bsum, dis, (const float4*)x, (const float4*)W0, bufA, N, SCAN_BLKS);

    // scan3 (scan2 replicated inside each block)
    scan3_k<<<dim3(SCAN_BLKS), blk, 0, stream>>>(off, bsum, cursor, N, E, SCAN_BLKS);

    // ---- CSR fill || H *= dis[row] ----
    fused_fill_k<<<dim3(FILL_BLOCKS + SCALE_BLOCKS), blk, 0, stream>>>(
        src, dst, cursor, esrc, (float4*)bufA, dis, N, E, FILL_BLOCKS);

    // ---- fused layers: gather + relu(bias,dis) + next GEMM ----
    layer_k<0><<<gLayer, blk, 0, stream>>>((const float4*)bufA, off, esrc, dis,
                                           b0, (const float4*)W1, nullptr, bufB, N);
    layer_k<0><<<gLayer, blk, 0, stream>>>((const float4*)bufB, off, esrc, dis,
                                           b1, (const float4*)W2, nullptr, bufA, N);
    // ---- final: gather + relu + projection ----
    layer_k<1><<<gLayer, blk, 0, stream>>>((const float4*)bufA, off, esrc, dis,
                                           b2, (const float4*)Wout, bout, out, N);
}

// Round 14
// 306.408 us; speedup vs baseline: 1.8075x; 1.2281x over previous
//
#include <hip/hip_runtime.h>
#include <hip/hip_bf16.h>

#define D 64
#define N_NODES 50000
#define N_EDGES 800000
#define TILE 16            // nodes per tile (N % 16 == 0 -> no tails anywhere)
#define SCAN_BLKS 196      // ceil(N/256)

// ---------------- degree histogram (standalone: atomics-only kernel) ----------------
__global__ void hist_k(const int* __restrict__ dst, int* __restrict__ cnt, int E) {
    int i = blockIdx.x * blockDim.x + threadIdx.x;
    if (i < E) atomicAdd(&cnt[dst[i]], 1);
}

// ---- helper: acc += s * w (componentwise) ----
__device__ __forceinline__ void fma4(float4& a, float s, float4 w) {
    a.x = fmaf(s, w.x, a.x);
    a.y = fmaf(s, w.y, a.y);
    a.z = fmaf(s, w.z, a.z);
    a.w = fmaf(s, w.w, a.w);
}

// ---- dense 16x64 tile GEMM out = hbuf @ W, optionally scaled by dis[row] ----
// PROVEN no-spill (36 VGPR inside layer_k). Do NOT widen to 2 rows/thread:
// rounds 12/13 showed the 2-row variant spills (VGPR 64, 245MB scratch WRITE).
template <int SCALED>
__device__ __forceinline__ void tile_gemm(const float (*hbuf)[68], const float4* __restrict__ W4,
                                          const float* __restrict__ dis, float* __restrict__ outp,
                                          int base, int t) {
    int lane = t & 63;
    int cg = lane & 15;
    int rr = (t >> 6) * 4 + (lane >> 4);
    float4 acc = make_float4(0.f, 0.f, 0.f, 0.f);
#pragma unroll
    for (int kk = 0; kk < 16; ++kk) {
        float4 hb = *(const float4*)&hbuf[rr][kk * 4];
        fma4(acc, hb.x, W4[(kk * 4 + 0) * 16 + cg]);
        fma4(acc, hb.y, W4[(kk * 4 + 1) * 16 + cg]);
        fma4(acc, hb.z, W4[(kk * 4 + 2) * 16 + cg]);
        fma4(acc, hb.w, W4[(kk * 4 + 3) * 16 + cg]);
    }
    if (SCALED) {
        float dv = dis[base + rr];
        acc.x *= dv; acc.y *= dv; acc.z *= dv; acc.w *= dv;
    }
    ((float4*)outp)[(size_t)(base + rr) * 16 + cg] = acc;
}

// ---------------- fused: scan1 (blocks < scanBlocks) || gemm0 (single-row tile) ----------------
// scan1: per-block exclusive scan of cnt -> off, block sums, dis = rsqrt(cnt+1)
// gemm0: H = x @ W0 (unscaled; scale fused into fill pass). Streaming+streaming: safe.
__global__ void scan1_gemm0_k(const int* __restrict__ cnt, int* __restrict__ off,
                              int* __restrict__ bsum, float* __restrict__ dis,
                              const float4* __restrict__ X4, const float4* __restrict__ W4,
                              float* __restrict__ H, int N, int scanBlocks) {
    __shared__ float hbuf[TILE][68];
    int bid = blockIdx.x;
    int t = threadIdx.x;
    if (bid < scanBlocks) {
        __shared__ int sh[256];
        int i = bid * 256 + t;
        int v = (i < N) ? cnt[i] : 0;
        sh[t] = v;
        __syncthreads();
#pragma unroll
        for (int d = 1; d < 256; d <<= 1) {
            int u = (t >= d) ? sh[t - d] : 0;
            __syncthreads();
            sh[t] += u;
            __syncthreads();
        }
        if (i < N) {
            off[i] = sh[t] - v;
            dis[i] = rsqrtf((float)v + 1.0f);  // +1 self loop
        }
        if (t == 255) bsum[bid] = sh[255];
    } else {
        int base = (bid - scanBlocks) * TILE;   // base <= 49984: always full tile
        int r = t >> 4, ch = t & 15;
        float4 v = X4[(size_t)(base + r) * 16 + ch];
        *(float4*)&hbuf[r][ch * 4] = v;
        __syncthreads();
        tile_gemm<0>(hbuf, W4, nullptr, H, base, t);
    }
}

// ---------------- scan3 (scan2 replicated per block): finalize off, init cursor ----------------
__global__ void scan3_k(int* __restrict__ off, const int* __restrict__ bsum,
                        int* __restrict__ cursor, int N, int E, int nb) {
    __shared__ int sh[256];
    int t = threadIdx.x;
    int v = (t < nb) ? bsum[t] : 0;
    sh[t] = v;
    __syncthreads();
#pragma unroll
    for (int d = 1; d < 256; d <<= 1) {
        int u = (t >= d) ? sh[t - d] : 0;
        __syncthreads();
        sh[t] += u;
        __syncthreads();
    }
    int add = (blockIdx.x == 0) ? 0 : sh[blockIdx.x - 1];
    int i = blockIdx.x * 256 + t;
    if (i < N) {
        int o = off[i] + add;
        off[i] = o;
        cursor[i] = o;
    }
    if (i == 0) off[N] = E;
}

// ---------------- fused: CSR fill (1 edge/thread) || H *= dis[row] ----------------
__global__ void fused_fill_k(const int* __restrict__ src, const int* __restrict__ dst,
                             int* __restrict__ cursor, int* __restrict__ esrc,
                             float4* __restrict__ H4, const float* __restrict__ dis,
                             int N, int E, int fillBlocks) {
    int bid = blockIdx.x;
    int t = threadIdx.x;
    if (bid < fillBlocks) {
        for (int i = bid * 256 + t; i < E; i += fillBlocks * 256) {
            int pos = atomicAdd(&cursor[dst[i]], 1);
            esrc[pos] = src[i];
        }
    } else {
        int sb = bid - fillBlocks;
        int nsb = gridDim.x - fillBlocks;
        int total = N * 16;  // float4 elements
        for (int i = sb * 256 + t; i < total; i += nsb * 256) {
            float4 v = H4[i];
            float dv = dis[i >> 4];
            v.x *= dv; v.y *= dv; v.z *= dv; v.w *= dv;
            H4[i] = v;
        }
    }
}

// ---------------- fused layer (round-11 proven, 36 VGPR): gather + activation + GEMM / projection ----------------
template <int FINAL>
__global__ void layer_k(const float4* __restrict__ Hs4, const int* __restrict__ off,
                        const int* __restrict__ esrc, const float* __restrict__ dis,
                        const float* __restrict__ bias, const float4* __restrict__ W4,
                        const float* __restrict__ bout, float* __restrict__ outp, int N) {
    __shared__ float hbuf[TILE][68];
    int t = threadIdx.x;
    int lane = t & 63;
    int w = t >> 6;
    int g = lane >> 4;
    int l16 = lane & 15;
    int rloc = w * 4 + g;
    int n = blockIdx.x * TILE + rloc;

    int beg = off[n], end = off[n + 1];
    float4 acc = Hs4[(size_t)n * 16 + l16];  // self-loop term
    int j = beg;
    for (; j + 8 <= end; j += 8) {
        int s0 = esrc[j],     s1 = esrc[j + 1], s2 = esrc[j + 2], s3 = esrc[j + 3];
        int s4 = esrc[j + 4], s5 = esrc[j + 5], s6 = esrc[j + 6], s7 = esrc[j + 7];
        float4 v0 = Hs4[(size_t)s0 * 16 + l16];
        float4 v1 = Hs4[(size_t)s1 * 16 + l16];
        float4 v2 = Hs4[(size_t)s2 * 16 + l16];
        float4 v3 = Hs4[(size_t)s3 * 16 + l16];
        float4 v4 = Hs4[(size_t)s4 * 16 + l16];
        float4 v5 = Hs4[(size_t)s5 * 16 + l16];
        float4 v6 = Hs4[(size_t)s6 * 16 + l16];
        float4 v7 = Hs4[(size_t)s7 * 16 + l16];
        acc.x += ((v0.x + v1.x) + (v2.x + v3.x)) + ((v4.x + v5.x) + (v6.x + v7.x));
        acc.y += ((v0.y + v1.y) + (v2.y + v3.y)) + ((v4.y + v5.y) + (v6.y + v7.y));
        acc.z += ((v0.z + v1.z) + (v2.z + v3.z)) + ((v4.z + v5.z) + (v6.z + v7.z));
        acc.w += ((v0.w + v1.w) + (v2.w + v3.w)) + ((v4.w + v5.w) + (v6.w + v7.w));
    }
    if (j < end) {
        int last = end - 1;
        int i1 = j + 1 <= last ? j + 1 : last;
        int i2 = j + 2 <= last ? j + 2 : last;
        int i3 = j + 3 <= last ? j + 3 : last;
        int i4 = j + 4 <= last ? j + 4 : last;
        int i5 = j + 5 <= last ? j + 5 : last;
        int i6 = j + 6 <= last ? j + 6 : last;
        int i7 = j + 7 <= last ? j + 7 : last;
        int s0 = esrc[j],  s1 = esrc[i1], s2 = esrc[i2], s3 = esrc[i3];
        int s4 = esrc[i4], s5 = esrc[i5], s6 = esrc[i6], s7 = esrc[i7];
        float m1 = (j + 1 < end) ? 1.f : 0.f;
        float m2 = (j + 2 < end) ? 1.f : 0.f;
        float m3 = (j + 3 < end) ? 1.f : 0.f;
        float m4 = (j + 4 < end) ? 1.f : 0.f;
        float m5 = (j + 5 < end) ? 1.f : 0.f;
        float m6 = (j + 6 < end) ? 1.f : 0.f;
        float m7 = (j + 7 < end) ? 1.f : 0.f;
        float4 v0 = Hs4[(size_t)s0 * 16 + l16];
        float4 v1 = Hs4[(size_t)s1 * 16 + l16];
        float4 v2 = Hs4[(size_t)s2 * 16 + l16];
        float4 v3 = Hs4[(size_t)s3 * 16 + l16];
        float4 v4 = Hs4[(size_t)s4 * 16 + l16];
        float4 v5 = Hs4[(size_t)s5 * 16 + l16];
        float4 v6 = Hs4[(size_t)s6 * 16 + l16];
        float4 v7 = Hs4[(size_t)s7 * 16 + l16];
        acc.x += v0.x; acc.y += v0.y; acc.z += v0.z; acc.w += v0.w;
        acc.x = fmaf(m1, v1.x, acc.x); acc.y = fmaf(m1, v1.y, acc.y); acc.z = fmaf(m1, v1.z, acc.z); acc.w = fmaf(m1, v1.w, acc.w);
        acc.x = fmaf(m2, v2.x, acc.x); acc.y = fmaf(m2, v2.y, acc.y); acc.z = fmaf(m2, v2.z, acc.z); acc.w = fmaf(m2, v2.w, acc.w);
        acc.x = fmaf(m3, v3.x, acc.x); acc.y = fmaf(m3, v3.y, acc.y); acc.z = fmaf(m3, v3.z, acc.z); acc.w = fmaf(m3, v3.w, acc.w);
        acc.x = fmaf(m4, v4.x, acc.x); acc.y = fmaf(m4, v4.y, acc.y); acc.z = fmaf(m4, v4.z, acc.z); acc.w = fmaf(m4, v4.w, acc.w);
        acc.x = fmaf(m5, v5.x, acc.x); acc.y = fmaf(m5, v5.y, acc.y); acc.z = fmaf(m5, v5.z, acc.z); acc.w = fmaf(m5, v5.w, acc.w);
        acc.x = fmaf(m6, v6.x, acc.x); acc.y = fmaf(m6, v6.y, acc.y); acc.z = fmaf(m6, v6.z, acc.z); acc.w = fmaf(m6, v6.w, acc.w);
        acc.x = fmaf(m7, v7.x, acc.x); acc.y = fmaf(m7, v7.y, acc.y); acc.z = fmaf(m7, v7.z, acc.z); acc.w = fmaf(m7, v7.w, acc.w);
    }

    // ---- activation: h = relu(agg * dis[n] + b) ----
    float dv = dis[n];
    float4 b4 = ((const float4*)bias)[l16];
    float4 h4;
    h4.x = fmaxf(fmaf(acc.x, dv, b4.x), 0.f);
    h4.y = fmaxf(fmaf(acc.y, dv, b4.y), 0.f);
    h4.z = fmaxf(fmaf(acc.z, dv, b4.z), 0.f);
    h4.w = fmaxf(fmaf(acc.w, dv, b4.w), 0.f);

    if (FINAL) {
        float4 w4 = ((const float4*)W4)[l16];
        float p = fmaf(h4.x, w4.x, fmaf(h4.y, w4.y, fmaf(h4.z, w4.z, h4.w * w4.w)));
        p += __shfl_xor(p, 1, 64);
        p += __shfl_xor(p, 2, 64);
        p += __shfl_xor(p, 4, 64);
        p += __shfl_xor(p, 8, 64);
        if (l16 == 0) outp[n] = p + bout[0];
    } else {
        *(float4*)&hbuf[rloc][l16 * 4] = h4;
        __syncthreads();
        tile_gemm<1>(hbuf, W4, dis, outp, blockIdx.x * TILE, t);
    }
}

extern "C" void kernel_launch(void* const* d_in, const int* in_sizes, int n_in,
                              void* d_out, int out_size, void* d_ws, size_t ws_size,
                              hipStream_t stream) {
    const float* x    = (const float*)d_in[0];
    const int*   ei   = (const int*)d_in[1];
    const float* W0   = (const float*)d_in[2];
    const float* b0   = (const float*)d_in[3];
    const float* W1   = (const float*)d_in[4];
    const float* b1   = (const float*)d_in[5];
    const float* W2   = (const float*)d_in[6];
    const float* b2   = (const float*)d_in[7];
    const float* Wout = (const float*)d_in[8];
    const float* bout = (const float*)d_in[9];
    float* out = (float*)d_out;

    const int N = N_NODES, E = N_EDGES;
    const int* src = ei;
    const int* dst = ei + E;

    // ws layout (byte offsets) — verified no overlaps:
    //   cnt    [0,        200000)
    //   off    [262144,   462148)   (N+1 ints)
    //   cursor [524288,   724288)
    //   dis    [786432,   986432)
    //   bsum   [1013760,  1014784)  (990 KiB)
    //   esrc   [1048576,  4248576)  (E ints)
    //   bufA   [5 MiB,    +12.8 MB)
    //   bufB   [18 MiB,   +12.8 MB)
    char* ws = (char*)d_ws;
    int*   cnt    = (int*)(ws);
    int*   off    = (int*)(ws + (256u << 10));
    int*   cursor = (int*)(ws + (512u << 10));
    float* dis    = (float*)(ws + (768u << 10));
    int*   bsum   = (int*)(ws + (990u << 10));
    int*   esrc   = (int*)(ws + (1u << 20));
    float* bufA   = (float*)(ws + (5u << 20));
    float* bufB   = (float*)(ws + (18u << 20));

    dim3 blk(256);
    dim3 gE((E + 255) / 256);        // 3125 (1 edge/thread)
    const int TILES = N / TILE;      // 3125 (exact)
    dim3 gTile(TILES);
    const int FILL_BLOCKS = 3125;
    const int SCALE_BLOCKS = 784;

    // ---- prelude ----
    hipMemsetAsync(cnt, 0, (size_t)N * sizeof(int), stream);
    hist_k<<<gE, blk, 0, stream>>>(dst, cnt, E);

    // scan1 (196 blocks) || gemm0 (3125 single-row tiles) — both streaming, no spill
    scan1_gemm0_k<<<dim3(SCAN_BLKS + TILES), blk, 0, stream>>>(
        cnt, off, bsum, dis, (const float4*)x, (const float4*)W0, bufA, N, SCAN_BLKS);

    // scan3 (scan2 replicated inside each block)
    scan3_k<<<dim3(SCAN_BLKS), blk, 0, stream>>>(off, bsum, cursor, N, E, SCAN_BLKS);

    // ---- CSR fill || H *= dis[row] ----
    fused_fill_k<<<dim3(FILL_BLOCKS + SCALE_BLOCKS), blk, 0, stream>>>(
        src, dst, cursor, esrc, (float4*)bufA, dis, N, E, FILL_BLOCKS);

    // ---- fused layers: gather + relu(bias,dis) + next GEMM ----
    layer_k<0><<<gTile, blk, 0, stream>>>((const float4*)bufA, off, esrc, dis,
                                          b0, (const float4*)W1, nullptr, bufB, N);
    layer_k<0><<<gTile, blk, 0, stream>>>((const float4*)bufB, off, esrc, dis,
                                          b1, (const float4*)W2, nullptr, bufA, N);
    // ---- final: gather + relu + projection ----
    layer_k<1><<<gTile, blk, 0, stream>>>((const float4*)bufA, off, esrc, dis,
                                          b2, (const float4*)Wout, bout, out, N);
}

// Round 15
// 284.491 us; speedup vs baseline: 1.9467x; 1.0770x over previous
//
#include <hip/hip_runtime.h>
#include <hip/hip_bf16.h>
#include <hip/hip_fp16.h>

#define D 64
#define N_NODES 50000
#define N_EDGES 800000
#define TILE 16            // nodes per tile (N % 16 == 0 -> no tails anywhere)
#define SCAN_BLKS 196      // ceil(N/256)

// H (inter-layer activations) stored as fp16: 4 halfs per lane = uint2 (8B).
// Row = 64 halfs = 128B = exactly one L2 line. All math stays f32; only the
// gather/store dtype is half. Error budget ~5e-4 added absmax vs 2.48e-3 threshold.

__device__ __forceinline__ float4 h4tof4(uint2 r) {
    __half2 a = *(__half2*)&r.x;
    __half2 b = *(__half2*)&r.y;
    float2 fa = __half22float2(a);
    float2 fb = __half22float2(b);
    return make_float4(fa.x, fa.y, fb.x, fb.y);
}

__device__ __forceinline__ uint2 f4toh4(float4 v) {
    __half2 a = __float22half2_rn(make_float2(v.x, v.y));
    __half2 b = __float22half2_rn(make_float2(v.z, v.w));
    uint2 r;
    r.x = *(unsigned int*)&a;
    r.y = *(unsigned int*)&b;
    return r;
}

// ---------------- degree histogram (standalone: atomics-only kernel) ----------------
__global__ void hist_k(const int* __restrict__ dst, int* __restrict__ cnt, int E) {
    int i = blockIdx.x * blockDim.x + threadIdx.x;
    if (i < E) atomicAdd(&cnt[dst[i]], 1);
}

// ---- helper: acc += s * w (componentwise) ----
__device__ __forceinline__ void fma4(float4& a, float s, float4 w) {
    a.x = fmaf(s, w.x, a.x);
    a.y = fmaf(s, w.y, a.y);
    a.z = fmaf(s, w.z, a.z);
    a.w = fmaf(s, w.w, a.w);
}

// ---- dense 16x64 tile GEMM out(fp16) = hbuf @ W, optionally scaled by dis[row] ----
// PROVEN no-spill single-row form (rounds 12/13: the 2-row variant spills).
template <int SCALED>
__device__ __forceinline__ void tile_gemm(const float (*hbuf)[68], const float4* __restrict__ W4,
                                          const float* __restrict__ dis, uint2* __restrict__ outp,
                                          int base, int t) {
    int lane = t & 63;
    int cg = lane & 15;
    int rr = (t >> 6) * 4 + (lane >> 4);
    float4 acc = make_float4(0.f, 0.f, 0.f, 0.f);
#pragma unroll
    for (int kk = 0; kk < 16; ++kk) {
        float4 hb = *(const float4*)&hbuf[rr][kk * 4];
        fma4(acc, hb.x, W4[(kk * 4 + 0) * 16 + cg]);
        fma4(acc, hb.y, W4[(kk * 4 + 1) * 16 + cg]);
        fma4(acc, hb.z, W4[(kk * 4 + 2) * 16 + cg]);
        fma4(acc, hb.w, W4[(kk * 4 + 3) * 16 + cg]);
    }
    if (SCALED) {
        float dv = dis[base + rr];
        acc.x *= dv; acc.y *= dv; acc.z *= dv; acc.w *= dv;
    }
    outp[(size_t)(base + rr) * 16 + cg] = f4toh4(acc);
}

// ---------------- fused: scan1 (blocks < scanBlocks) || gemm0 (single-row tile) ----------------
__global__ void scan1_gemm0_k(const int* __restrict__ cnt, int* __restrict__ off,
                              int* __restrict__ bsum, float* __restrict__ dis,
                              const float4* __restrict__ X4, const float4* __restrict__ W4,
                              uint2* __restrict__ H, int N, int scanBlocks) {
    __shared__ float hbuf[TILE][68];
    int bid = blockIdx.x;
    int t = threadIdx.x;
    if (bid < scanBlocks) {
        __shared__ int sh[256];
        int i = bid * 256 + t;
        int v = (i < N) ? cnt[i] : 0;
        sh[t] = v;
        __syncthreads();
#pragma unroll
        for (int d = 1; d < 256; d <<= 1) {
            int u = (t >= d) ? sh[t - d] : 0;
            __syncthreads();
            sh[t] += u;
            __syncthreads();
        }
        if (i < N) {
            off[i] = sh[t] - v;
            dis[i] = rsqrtf((float)v + 1.0f);  // +1 self loop
        }
        if (t == 255) bsum[bid] = sh[255];
    } else {
        int base = (bid - scanBlocks) * TILE;   // base <= 49984: always full tile
        int r = t >> 4, ch = t & 15;
        float4 v = X4[(size_t)(base + r) * 16 + ch];
        *(float4*)&hbuf[r][ch * 4] = v;
        __syncthreads();
        tile_gemm<0>(hbuf, W4, nullptr, H, base, t);
    }
}

// ---------------- scan3 (scan2 replicated per block): finalize off, init cursor ----------------
__global__ void scan3_k(int* __restrict__ off, const int* __restrict__ bsum,
                        int* __restrict__ cursor, int N, int E, int nb) {
    __shared__ int sh[256];
    int t = threadIdx.x;
    int v = (t < nb) ? bsum[t] : 0;
    sh[t] = v;
    __syncthreads();
#pragma unroll
    for (int d = 1; d < 256; d <<= 1) {
        int u = (t >= d) ? sh[t - d] : 0;
        __syncthreads();
        sh[t] += u;
        __syncthreads();
    }
    int add = (blockIdx.x == 0) ? 0 : sh[blockIdx.x - 1];
    int i = blockIdx.x * 256 + t;
    if (i < N) {
        int o = off[i] + add;
        off[i] = o;
        cursor[i] = o;
    }
    if (i == 0) off[N] = E;
}

// ---------------- fused: CSR fill (1 edge/thread) || H *= dis[row] (fp16 in/out) ----------------
__global__ void fused_fill_k(const int* __restrict__ src, const int* __restrict__ dst,
                             int* __restrict__ cursor, int* __restrict__ esrc,
                             uint2* __restrict__ H2, const float* __restrict__ dis,
                             int N, int E, int fillBlocks) {
    int bid = blockIdx.x;
    int t = threadIdx.x;
    if (bid < fillBlocks) {
        for (int i = bid * 256 + t; i < E; i += fillBlocks * 256) {
            int pos = atomicAdd(&cursor[dst[i]], 1);
            esrc[pos] = src[i];
        }
    } else {
        int sb = bid - fillBlocks;
        int nsb = gridDim.x - fillBlocks;
        int total = N * 16;  // uint2 elements
        for (int i = sb * 256 + t; i < total; i += nsb * 256) {
            float4 v = h4tof4(H2[i]);
            float dv = dis[i >> 4];
            v.x *= dv; v.y *= dv; v.z *= dv; v.w *= dv;
            H2[i] = f4toh4(v);
        }
    }
}

// ---------------- fused layer: group-gather(fp16) + activation + tile GEMM / projection ----------------
template <int FINAL>
__global__ void layer_k(const uint2* __restrict__ Hs2, const int* __restrict__ off,
                        const int* __restrict__ esrc, const float* __restrict__ dis,
                        const float* __restrict__ bias, const float4* __restrict__ W4,
                        const float* __restrict__ bout, void* __restrict__ outp, int N) {
    __shared__ float hbuf[TILE][68];
    int t = threadIdx.x;
    int lane = t & 63;
    int w = t >> 6;
    int g = lane >> 4;
    int l16 = lane & 15;
    int rloc = w * 4 + g;
    int n = blockIdx.x * TILE + rloc;

    int beg = off[n], end = off[n + 1];
    float4 acc = h4tof4(Hs2[(size_t)n * 16 + l16]);  // self-loop term
    int j = beg;
    for (; j + 8 <= end; j += 8) {
        int s0 = esrc[j],     s1 = esrc[j + 1], s2 = esrc[j + 2], s3 = esrc[j + 3];
        int s4 = esrc[j + 4], s5 = esrc[j + 5], s6 = esrc[j + 6], s7 = esrc[j + 7];
        uint2 r0 = Hs2[(size_t)s0 * 16 + l16];
        uint2 r1 = Hs2[(size_t)s1 * 16 + l16];
        uint2 r2 = Hs2[(size_t)s2 * 16 + l16];
        uint2 r3 = Hs2[(size_t)s3 * 16 + l16];
        uint2 r4 = Hs2[(size_t)s4 * 16 + l16];
        uint2 r5 = Hs2[(size_t)s5 * 16 + l16];
        uint2 r6 = Hs2[(size_t)s6 * 16 + l16];
        uint2 r7 = Hs2[(size_t)s7 * 16 + l16];
        float4 v0 = h4tof4(r0), v1 = h4tof4(r1), v2 = h4tof4(r2), v3 = h4tof4(r3);
        float4 v4 = h4tof4(r4), v5 = h4tof4(r5), v6 = h4tof4(r6), v7 = h4tof4(r7);
        acc.x += ((v0.x + v1.x) + (v2.x + v3.x)) + ((v4.x + v5.x) + (v6.x + v7.x));
        acc.y += ((v0.y + v1.y) + (v2.y + v3.y)) + ((v4.y + v5.y) + (v6.y + v7.y));
        acc.z += ((v0.z + v1.z) + (v2.z + v3.z)) + ((v4.z + v5.z) + (v6.z + v7.z));
        acc.w += ((v0.w + v1.w) + (v2.w + v3.w)) + ((v4.w + v5.w) + (v6.w + v7.w));
    }
    if (j < end) {
        int last = end - 1;
        int i1 = j + 1 <= last ? j + 1 : last;
        int i2 = j + 2 <= last ? j + 2 : last;
        int i3 = j + 3 <= last ? j + 3 : last;
        int i4 = j + 4 <= last ? j + 4 : last;
        int i5 = j + 5 <= last ? j + 5 : last;
        int i6 = j + 6 <= last ? j + 6 : last;
        int i7 = j + 7 <= last ? j + 7 : last;
        int s0 = esrc[j],  s1 = esrc[i1], s2 = esrc[i2], s3 = esrc[i3];
        int s4 = esrc[i4], s5 = esrc[i5], s6 = esrc[i6], s7 = esrc[i7];
        float m1 = (j + 1 < end) ? 1.f : 0.f;
        float m2 = (j + 2 < end) ? 1.f : 0.f;
        float m3 = (j + 3 < end) ? 1.f : 0.f;
        float m4 = (j + 4 < end) ? 1.f : 0.f;
        float m5 = (j + 5 < end) ? 1.f : 0.f;
        float m6 = (j + 6 < end) ? 1.f : 0.f;
        float m7 = (j + 7 < end) ? 1.f : 0.f;
        uint2 r0 = Hs2[(size_t)s0 * 16 + l16];
        uint2 r1 = Hs2[(size_t)s1 * 16 + l16];
        uint2 r2 = Hs2[(size_t)s2 * 16 + l16];
        uint2 r3 = Hs2[(size_t)s3 * 16 + l16];
        uint2 r4 = Hs2[(size_t)s4 * 16 + l16];
        uint2 r5 = Hs2[(size_t)s5 * 16 + l16];
        uint2 r6 = Hs2[(size_t)s6 * 16 + l16];
        uint2 r7 = Hs2[(size_t)s7 * 16 + l16];
        float4 v0 = h4tof4(r0), v1 = h4tof4(r1), v2 = h4tof4(r2), v3 = h4tof4(r3);
        float4 v4 = h4tof4(r4), v5 = h4tof4(r5), v6 = h4tof4(r6), v7 = h4tof4(r7);
        acc.x += v0.x; acc.y += v0.y; acc.z += v0.z; acc.w += v0.w;
        acc.x = fmaf(m1, v1.x, acc.x); acc.y = fmaf(m1, v1.y, acc.y); acc.z = fmaf(m1, v1.z, acc.z); acc.w = fmaf(m1, v1.w, acc.w);
        acc.x = fmaf(m2, v2.x, acc.x); acc.y = fmaf(m2, v2.y, acc.y); acc.z = fmaf(m2, v2.z, acc.z); acc.w = fmaf(m2, v2.w, acc.w);
        acc.x = fmaf(m3, v3.x, acc.x); acc.y = fmaf(m3, v3.y, acc.y); acc.z = fmaf(m3, v3.z, acc.z); acc.w = fmaf(m3, v3.w, acc.w);
        acc.x = fmaf(m4, v4.x, acc.x); acc.y = fmaf(m4, v4.y, acc.y); acc.z = fmaf(m4, v4.z, acc.z); acc.w = fmaf(m4, v4.w, acc.w);
        acc.x = fmaf(m5, v5.x, acc.x); acc.y = fmaf(m5, v5.y, acc.y); acc.z = fmaf(m5, v5.z, acc.z); acc.w = fmaf(m5, v5.w, acc.w);
        acc.x = fmaf(m6, v6.x, acc.x); acc.y = fmaf(m6, v6.y, acc.y); acc.z = fmaf(m6, v6.z, acc.z); acc.w = fmaf(m6, v6.w, acc.w);
        acc.x = fmaf(m7, v7.x, acc.x); acc.y = fmaf(m7, v7.y, acc.y); acc.z = fmaf(m7, v7.z, acc.z); acc.w = fmaf(m7, v7.w, acc.w);
    }

    // ---- activation: h = relu(agg * dis[n] + b)  (all f32) ----
    float dv = dis[n];
    float4 b4 = ((const float4*)bias)[l16];
    float4 h4;
    h4.x = fmaxf(fmaf(acc.x, dv, b4.x), 0.f);
    h4.y = fmaxf(fmaf(acc.y, dv, b4.y), 0.f);
    h4.z = fmaxf(fmaf(acc.z, dv, b4.z), 0.f);
    h4.w = fmaxf(fmaf(acc.w, dv, b4.w), 0.f);

    if (FINAL) {
        float4 w4 = ((const float4*)W4)[l16];
        float p = fmaf(h4.x, w4.x, fmaf(h4.y, w4.y, fmaf(h4.z, w4.z, h4.w * w4.w)));
        p += __shfl_xor(p, 1, 64);
        p += __shfl_xor(p, 2, 64);
        p += __shfl_xor(p, 4, 64);
        p += __shfl_xor(p, 8, 64);
        if (l16 == 0) ((float*)outp)[n] = p + bout[0];
    } else {
        *(float4*)&hbuf[rloc][l16 * 4] = h4;
        __syncthreads();
        tile_gemm<1>(hbuf, W4, dis, (uint2*)outp, blockIdx.x * TILE, t);
    }
}

extern "C" void kernel_launch(void* const* d_in, const int* in_sizes, int n_in,
                              void* d_out, int out_size, void* d_ws, size_t ws_size,
                              hipStream_t stream) {
    const float* x    = (const float*)d_in[0];
    const int*   ei   = (const int*)d_in[1];
    const float* W0   = (const float*)d_in[2];
    const float* b0   = (const float*)d_in[3];
    const float* W1   = (const float*)d_in[4];
    const float* b1   = (const float*)d_in[5];
    const float* W2   = (const float*)d_in[6];
    const float* b2   = (const float*)d_in[7];
    const float* Wout = (const float*)d_in[8];
    const float* bout = (const float*)d_in[9];
    float* out = (float*)d_out;

    const int N = N_NODES, E = N_EDGES;
    const int* src = ei;
    const int* dst = ei + E;

    // ws layout (byte offsets) — verified no overlaps:
    //   cnt    [0,        200000)
    //   off    [262144,   462148)   (N+1 ints)
    //   cursor [524288,   724288)
    //   dis    [786432,   986432)
    //   bsum   [1013760,  1014784)  (990 KiB)
    //   esrc   [1048576,  4248576)  (E ints)
    //   bufA   [5 MiB,    +6.4 MB)  (fp16 H)
    //   bufB   [18 MiB,   +6.4 MB)  (fp16 H)
    char* ws = (char*)d_ws;
    int*   cnt    = (int*)(ws);
    int*   off    = (int*)(ws + (256u << 10));
    int*   cursor = (int*)(ws + (512u << 10));
    float* dis    = (float*)(ws + (768u << 10));
    int*   bsum   = (int*)(ws + (990u << 10));
    int*   esrc   = (int*)(ws + (1u << 20));
    uint2* bufA   = (uint2*)(ws + (5u << 20));
    uint2* bufB   = (uint2*)(ws + (18u << 20));

    dim3 blk(256);
    dim3 gE((E + 255) / 256);        // 3125 (1 edge/thread)
    const int TILES = N / TILE;      // 3125 (exact)
    dim3 gTile(TILES);
    const int FILL_BLOCKS = 3125;
    const int SCALE_BLOCKS = 784;

    // ---- prelude ----
    hipMemsetAsync(cnt, 0, (size_t)N * sizeof(int), stream);
    hist_k<<<gE, blk, 0, stream>>>(dst, cnt, E);

    // scan1 (196 blocks) || gemm0 (3125 single-row tiles) — both streaming, no spill
    scan1_gemm0_k<<<dim3(SCAN_BLKS + TILES), blk, 0, stream>>>(
        cnt, off, bsum, dis, (const float4*)x, (const float4*)W0, bufA, N, SCAN_BLKS);

    // scan3 (scan2 replicated inside each block)
    scan3_k<<<dim3(SCAN_BLKS), blk, 0, stream>>>(off, bsum, cursor, N, E, SCAN_BLKS);

    // ---- CSR fill || H *= dis[row] ----
    fused_fill_k<<<dim3(FILL_BLOCKS + SCALE_BLOCKS), blk, 0, stream>>>(
        src, dst, cursor, esrc, bufA, dis, N, E, FILL_BLOCKS);

    // ---- fused layers: gather + relu(bias,dis) + next GEMM ----
    layer_k<0><<<gTile, blk, 0, stream>>>(bufA, off, esrc, dis,
                                          b0, (const float4*)W1, nullptr, bufB, N);
    layer_k<0><<<gTile, blk, 0, stream>>>(bufB, off, esrc, dis,
                                          b1, (const float4*)W2, nullptr, bufA, N);
    // ---- final: gather + relu + projection ----
    layer_k<1><<<gTile, blk, 0, stream>>>(bufA, off, esrc, dis,
                                          b2, (const float4*)Wout, bout, out, N);
}